// Round 3
// baseline (1111.575 us; speedup 1.0000x reference)
//
#include <hip/hip_runtime.h>

#define NN 50000
#define NE 1600000
#define F 32
#define T 4
#define FT 8
#define ED 16
#define NLAYERS 5

// ---------------- CSR build (once per call; edge_index constant across layers) ----

__global__ void zero_cnt(int* __restrict__ cnt) {
    int i = blockIdx.x * 256 + threadIdx.x;
    if (i < NN) cnt[i] = 0;
}

__global__ void count_kernel(const int* __restrict__ ei, int* __restrict__ cnt) {
    int e = blockIdx.x * 256 + threadIdx.x;
    if (e >= NE) return;
    atomicAdd(&cnt[ei[NE + e]], 1);
}

// one-block exclusive scan over cnt[NN] -> row_ptr, cursor (1024 threads)
__global__ void scan_kernel(const int* __restrict__ cnt, int* __restrict__ row_ptr,
                            int* __restrict__ cursor) {
    __shared__ int wsum[16];
    __shared__ int carry_s;
    int tid = threadIdx.x;
    int lane = tid & 63, wid = tid >> 6;
    if (tid == 0) carry_s = 0;
    __syncthreads();
    for (int base = 0; base < NN; base += 1024) {
        int i = base + tid;
        int v = (i < NN) ? cnt[i] : 0;
        int s = v;
#pragma unroll
        for (int off = 1; off < 64; off <<= 1) {
            int tt = __shfl_up(s, off, 64);
            if (lane >= off) s += tt;
        }
        __syncthreads();
        if (lane == 63) wsum[wid] = s;
        __syncthreads();
        if (wid == 0 && lane < 16) {
            int w = wsum[lane];
            int ws = w;
#pragma unroll
            for (int off = 1; off < 16; off <<= 1) {
                int tt = __shfl_up(ws, off, 16);
                if (lane >= off) ws += tt;
            }
            wsum[lane] = ws - w;
        }
        __syncthreads();
        int excl = carry_s + wsum[wid] + s - v;
        if (i < NN) { row_ptr[i] = excl; cursor[i] = excl; }
        __syncthreads();
        if (tid == 1023) carry_s += wsum[15] + s;
    }
}

__global__ void scatter_kernel(const int* __restrict__ ei, int* __restrict__ cursor,
                               int* __restrict__ eid_s, int* __restrict__ src_s) {
    int e = blockIdx.x * 256 + threadIdx.x;
    if (e >= NE) return;
    int dst = ei[NE + e];
    int p = atomicAdd(&cursor[dst], 1);
    eid_s[p] = e;
    src_s[p] = ei[e];
}

// eattr_perm[i] = eattr[eid_s[i]]  (one thread per float4)
__global__ void permute_eattr(const int* __restrict__ eid_s,
                              const float* __restrict__ eattr,
                              float* __restrict__ outp) {
    int idx = blockIdx.x * 256 + threadIdx.x;
    if (idx >= NE * 4) return;
    int i = idx >> 2, q = idx & 3;
    int e = eid_s[i];
    ((float4*)outp)[idx] = ((const float4*)eattr)[(size_t)e * 4 + q];
}

// ---------------- per-layer kernels ----------------

// Wc[k][ch] = sum_j eW[k][j] * preW_ee[t][j][f]   (16x32)
__global__ void wc_kernel(const float* __restrict__ eW, const float* __restrict__ preW,
                          float* __restrict__ Wc) {
    int idx = threadIdx.x;
    if (idx >= 512) return;
    int k = idx >> 5, ch = idx & 31;
    int t = ch >> 3, f = ch & 7;
    float sum = 0.f;
#pragma unroll
    for (int j = 0; j < 8; j++) sum += eW[k * 8 + j] * preW[(t * 24 + 16 + j) * 8 + f];
    Wc[k * 32 + ch] = sum;
}

// a[n][ch] = preW_xi . xt + preb + (eb . preW_ee) ;  b[n][ch] = preW_xj . xt
__global__ void node_pre(const float* __restrict__ xin,
                         const float* __restrict__ preW, const float* __restrict__ preb,
                         const float* __restrict__ ebias,
                         float* __restrict__ a, float* __restrict__ b) {
    int idx = blockIdx.x * 256 + threadIdx.x;
    if (idx >= NN * F) return;
    int n = idx >> 5, ch = idx & 31;
    int t = ch >> 3, f = ch & 7;
    const float* xrow = xin + n * F + t * FT;
    const float* wA = preW + (t * 24) * 8 + f;
    const float* wB = preW + (t * 24 + 8) * 8 + f;
    float av = preb[t * 8 + f];
#pragma unroll
    for (int j = 0; j < 8; j++) av += ebias[j] * preW[(t * 24 + 16 + j) * 8 + f];
    float bv = 0.f;
#pragma unroll
    for (int k = 0; k < 8; k++) {
        float xv = xrow[k];
        av += xv * wA[k * 8];
        bv += xv * wB[k * 8];
    }
    a[idx] = av;
    b[idx] = bv;
}

// one wave per dst node; 32 lanes = channels, 2 halves = 2 edges per iteration.
// ea points at eattr_perm (CSR order, read with index i) when eid==nullptr,
// else at the original eattr (indexed via eid[i]).
__global__ __launch_bounds__(256) void gather_post(
        const float* __restrict__ xin, const float* __restrict__ a,
        const float* __restrict__ b, const float* __restrict__ ea,
        const int* __restrict__ eid,
        const int* __restrict__ row_ptr, const int* __restrict__ cnt,
        const int* __restrict__ src_s,
        const float* __restrict__ Wc,
        const float* __restrict__ postW, const float* __restrict__ postb,
        const float* __restrict__ linW, const float* __restrict__ linb,
        float* __restrict__ xout) {
    __shared__ float cat[4][128];
    __shared__ float um[4][32];
    int tid = threadIdx.x;
    int wv = tid >> 6;
    int lane = tid & 63;
    int ch = lane & 31, half = lane >> 5;
    int n = blockIdx.x * 4 + wv;           // NN divisible by 4
    int t = ch >> 3, f = ch & 7;

    float wc[16];
#pragma unroll
    for (int k = 0; k < 16; k++) wc[k] = Wc[k * 32 + ch];
    float a_val = a[n * F + ch];
    int rs = row_ptr[n], deg = cnt[n];

    float S = 0.f, M = -3.4e38f;
    for (int i = rs + half; i < rs + deg; i += 2) {
        int s = src_s[i];
        size_t row = eid ? (size_t)eid[i] : (size_t)i;
        const float4* ep = (const float4*)(ea + row * ED);
        float4 e0 = ep[0], e1 = ep[1], e2 = ep[2], e3 = ep[3];
        float bv = b[s * F + ch];
        float c = e0.x * wc[0] + e0.y * wc[1] + e0.z * wc[2] + e0.w * wc[3]
                + e1.x * wc[4] + e1.y * wc[5] + e1.z * wc[6] + e1.w * wc[7]
                + e2.x * wc[8] + e2.y * wc[9] + e2.z * wc[10] + e2.w * wc[11]
                + e3.x * wc[12] + e3.y * wc[13] + e3.z * wc[14] + e3.w * wc[15];
        float h = bv + c;
        S += h;
        M = fmaxf(M, h);
    }
    S += __shfl_xor(S, 32, 64);
    M = fmaxf(M, __shfl_xor(M, 32, 64));

    float xv = xin[n * F + ch];
    float sum_h, mean_h, max_h;
    if (deg > 0) {
        sum_h = S + (float)deg * a_val;
        mean_h = sum_h / (float)deg;
        max_h = M + a_val;
    } else {
        sum_h = 0.f; mean_h = 0.f; max_h = 0.f;
    }
    if (half == 0) {
        cat[wv][0 * 32 + ch] = xv;
        cat[wv][1 * 32 + ch] = mean_h;
        cat[wv][2 * 32 + ch] = sum_h;
        cat[wv][3 * 32 + ch] = max_h;
    }
    __syncthreads();
    if (half == 0) {
        float u = postb[t * 8 + f];
#pragma unroll
        for (int k = 0; k < 32; k++) {
            int g = k >> 3, kk = k & 7;
            u += cat[wv][g * 32 + t * 8 + kk] * postW[(t * 32 + k) * 8 + f];
        }
        um[wv][ch] = u;
    }
    __syncthreads();
    if (half == 0) {
        float y = linb[ch];
#pragma unroll
        for (int k = 0; k < 32; k++) y += um[wv][k] * linW[k * 32 + ch];
        xout[(size_t)n * F + ch] = fmaxf(y, 0.f);
    }
}

// ---------------- launch ----------------

extern "C" void kernel_launch(void* const* d_in, const int* in_sizes, int n_in,
                              void* d_out, int out_size, void* d_ws, size_t ws_size,
                              hipStream_t stream) {
    const float* x      = (const float*)d_in[0];
    const int*   ei     = (const int*)d_in[1];
    const float* eattr  = (const float*)d_in[2];
    const float* edge_W = (const float*)d_in[3];
    const float* edge_b = (const float*)d_in[4];
    const float* pre_W  = (const float*)d_in[5];
    const float* pre_b  = (const float*)d_in[6];
    const float* post_W = (const float*)d_in[7];
    const float* post_b = (const float*)d_in[8];
    const float* lin_W  = (const float*)d_in[9];
    const float* lin_b  = (const float*)d_in[10];
    float* out = (float*)d_out;

    const size_t NC = (size_t)NN * F;
    char* p = (char*)d_ws;
    int* cnt     = (int*)p;            p += sizeof(int) * NN;
    int* row_ptr = (int*)p;            p += sizeof(int) * NN;
    int* cursor  = (int*)p;            p += sizeof(int) * NN;
    int* eid_s   = (int*)p;            p += sizeof(int) * NE;
    int* src_s   = (int*)p;            p += sizeof(int) * NE;
    float* a     = (float*)p;          p += sizeof(float) * NC;
    float* b     = (float*)p;          p += sizeof(float) * NC;
    float* Wc    = (float*)p;          p += sizeof(float) * 16 * 32;
    float* xb0   = (float*)p;          p += sizeof(float) * NC;
    float* xb1   = (float*)p;          p += sizeof(float) * NC;
    float* ea_pm = (float*)p;          p += sizeof(float) * (size_t)NE * ED;
    bool use_perm = ((size_t)(p - (char*)d_ws) <= ws_size);

    dim3 blk(256);
    int gN  = (NN + 255) / 256;
    int gE  = (NE + 255) / 256;
    int gE4 = (NE * 4 + 255) / 256;
    int gNC = (NN * F + 255) / 256;
    int gG  = NN / 4;

    // CSR build (once; reused by all 5 layers)
    hipLaunchKernelGGL(zero_cnt,      dim3(gN), blk, 0, stream, cnt);
    hipLaunchKernelGGL(count_kernel,  dim3(gE), blk, 0, stream, ei, cnt);
    hipLaunchKernelGGL(scan_kernel,   dim3(1), dim3(1024), 0, stream, cnt, row_ptr, cursor);
    hipLaunchKernelGGL(scatter_kernel,dim3(gE), blk, 0, stream, ei, cursor, eid_s, src_s);
    if (use_perm)
        hipLaunchKernelGGL(permute_eattr, dim3(gE4), blk, 0, stream, eid_s, eattr, ea_pm);

    const float* ea_use = use_perm ? ea_pm : eattr;
    const int*   eid_use = use_perm ? nullptr : eid_s;

    const float* xin = x;
    for (int l = 0; l < NLAYERS; l++) {
        const float* eW  = edge_W + (size_t)l * ED * FT;
        const float* eb  = edge_b + (size_t)l * FT;
        const float* pW  = pre_W  + (size_t)l * T * 24 * FT;
        const float* pb  = pre_b  + (size_t)l * T * FT;
        const float* poW = post_W + (size_t)l * T * 32 * FT;
        const float* pob = post_b + (size_t)l * T * FT;
        const float* lW  = lin_W  + (size_t)l * F * F;
        const float* lb  = lin_b  + (size_t)l * F;
        float* xout = (l == NLAYERS - 1) ? out : ((l & 1) ? xb1 : xb0);

        hipLaunchKernelGGL(wc_kernel, dim3(1), dim3(512), 0, stream, eW, pW, Wc);
        hipLaunchKernelGGL(node_pre,  dim3(gNC), blk, 0, stream, xin, pW, pb, eb, a, b);
        hipLaunchKernelGGL(gather_post, dim3(gG), blk, 0, stream,
                           xin, a, b, ea_use, eid_use, row_ptr, cnt, src_s, Wc,
                           poW, pob, lW, lb, xout);
        xin = xout;
    }
}

// Round 4
// 920.685 us; speedup vs baseline: 1.2073x; 1.2073x over previous
//
#include <hip/hip_runtime.h>
#include <hip/hip_fp16.h>

#define NN 50000
#define NE 1600000
#define F 32
#define T 4
#define FT 8
#define ED 16
#define NLAYERS 5

// ---------------- CSR build (once per call; edge_index constant across layers) ----

__global__ void zero_cnt(int* __restrict__ cnt) {
    int i = blockIdx.x * 256 + threadIdx.x;
    if (i < NN) cnt[i] = 0;
}

__global__ void count_kernel(const int* __restrict__ ei, int* __restrict__ cnt) {
    int e = blockIdx.x * 256 + threadIdx.x;
    if (e >= NE) return;
    atomicAdd(&cnt[ei[NE + e]], 1);
}

// one-block exclusive scan over cnt[NN] -> row_ptr, cursor (1024 threads)
__global__ void scan_kernel(const int* __restrict__ cnt, int* __restrict__ row_ptr,
                            int* __restrict__ cursor) {
    __shared__ int wsum[16];
    __shared__ int carry_s;
    int tid = threadIdx.x;
    int lane = tid & 63, wid = tid >> 6;
    if (tid == 0) carry_s = 0;
    __syncthreads();
    for (int base = 0; base < NN; base += 1024) {
        int i = base + tid;
        int v = (i < NN) ? cnt[i] : 0;
        int s = v;
#pragma unroll
        for (int off = 1; off < 64; off <<= 1) {
            int tt = __shfl_up(s, off, 64);
            if (lane >= off) s += tt;
        }
        __syncthreads();
        if (lane == 63) wsum[wid] = s;
        __syncthreads();
        if (wid == 0 && lane < 16) {
            int w = wsum[lane];
            int ws = w;
#pragma unroll
            for (int off = 1; off < 16; off <<= 1) {
                int tt = __shfl_up(ws, off, 16);
                if (lane >= off) ws += tt;
            }
            wsum[lane] = ws - w;
        }
        __syncthreads();
        int excl = carry_s + wsum[wid] + s - v;
        if (i < NN) { row_ptr[i] = excl; cursor[i] = excl; }
        __syncthreads();
        if (tid == 1023) carry_s += wsum[15] + s;
    }
}

__global__ void scatter_kernel(const int* __restrict__ ei, int* __restrict__ cursor,
                               int* __restrict__ eid_s, int* __restrict__ src_s) {
    int e = blockIdx.x * 256 + threadIdx.x;
    if (e >= NE) return;
    int dst = ei[NE + e];
    int p = atomicAdd(&cursor[dst], 1);
    eid_s[p] = e;
    src_s[p] = ei[e];
}

// ---------------- one-time: project eattr through all 5 layers' edge encoders ----
// ee_pm[l][i][0..7] (fp16) = eattr[eid_s[i]] @ eW[l] + eb[l], stored in CSR order.
__global__ void proj_edges(const int* __restrict__ eid_s,
                           const float* __restrict__ eattr,
                           const float* __restrict__ edge_W,  // [L,16,8]
                           const float* __restrict__ edge_b,  // [L,8]
                           float4* __restrict__ ee_pm) {      // [L][NE] float4 (=8 half)
    __shared__ float sW[NLAYERS * ED * FT];   // 640
    __shared__ float sB[NLAYERS * FT];        // 40
    int tid = threadIdx.x;
    for (int k = tid; k < NLAYERS * ED * FT; k += 256) sW[k] = edge_W[k];
    for (int k = tid; k < NLAYERS * FT; k += 256) sB[k] = edge_b[k];
    __syncthreads();
    int i = blockIdx.x * 256 + tid;
    if (i >= NE) return;
    int e = eid_s[i];
    float ea[16];
    const float4* eap = (const float4*)(eattr + (size_t)e * ED);
#pragma unroll
    for (int q = 0; q < 4; q++) {
        float4 v = eap[q];
        ea[q * 4 + 0] = v.x; ea[q * 4 + 1] = v.y;
        ea[q * 4 + 2] = v.z; ea[q * 4 + 3] = v.w;
    }
#pragma unroll
    for (int l = 0; l < NLAYERS; l++) {
        float v[8];
#pragma unroll
        for (int j = 0; j < 8; j++) v[j] = sB[l * 8 + j];
#pragma unroll
        for (int k = 0; k < 16; k++) {
            float av = ea[k];
#pragma unroll
            for (int j = 0; j < 8; j++) v[j] += av * sW[l * 128 + k * 8 + j];
        }
        union { __half h[8]; float4 f4; } u;
#pragma unroll
        for (int j = 0; j < 8; j++) u.h[j] = __float2half(v[j]);
        ee_pm[(size_t)l * NE + i] = u.f4;
    }
}

// ---------------- per-layer kernels ----------------

__device__ __forceinline__ unsigned short f2bf_rne(float v) {
    unsigned u = __float_as_uint(v);
    return (unsigned short)((u + 0x7FFFu + ((u >> 16) & 1u)) >> 16);
}

// a[n][ch] = preW_xi . xt + preb ;  b16[n][ch] = bf16(preW_xj . xt)
__global__ void node_pre(const float* __restrict__ xin,
                         const float* __restrict__ preW, const float* __restrict__ preb,
                         float* __restrict__ a, unsigned short* __restrict__ b16) {
    int idx = blockIdx.x * 256 + threadIdx.x;
    if (idx >= NN * F) return;
    int n = idx >> 5, ch = idx & 31;
    int t = ch >> 3, f = ch & 7;
    const float* xrow = xin + n * F + t * FT;
    const float* wA = preW + (t * 24) * 8 + f;
    const float* wB = preW + (t * 24 + 8) * 8 + f;
    float av = preb[t * 8 + f];
    float bv = 0.f;
#pragma unroll
    for (int k = 0; k < 8; k++) {
        float xv = xrow[k];
        av += xv * wA[k * 8];
        bv += xv * wB[k * 8];
    }
    a[idx] = av;
    b16[idx] = f2bf_rne(bv);
}

// one wave per dst node; 32 lanes = channels, 2 halves alternate edges.
// 2-deep software pipeline: src/ee loaded 2 iters ahead, b 1-2 iters ahead.
__global__ __launch_bounds__(256) void gather_post(
        const float* __restrict__ xin, const float* __restrict__ a,
        const unsigned short* __restrict__ b16,
        const float4* __restrict__ ee_l,      // this layer's fp16 ee, CSR order
        const int* __restrict__ row_ptr, const int* __restrict__ cnt,
        const int* __restrict__ src_s,
        const float* __restrict__ preW,       // for wc8 = preW_ee[t][:,f]
        const float* __restrict__ postW, const float* __restrict__ postb,
        const float* __restrict__ linW, const float* __restrict__ linb,
        float* __restrict__ xout) {
    __shared__ float cat[4][128];
    __shared__ float um[4][32];
    int tid = threadIdx.x;
    int wv = tid >> 6;
    int lane = tid & 63;
    int ch = lane & 31, half = lane >> 5;
    int n = blockIdx.x * 4 + wv;            // NN divisible by 4
    int t = ch >> 3, f = ch & 7;

    float wc8[8];
#pragma unroll
    for (int j = 0; j < 8; j++) wc8[j] = preW[(t * 24 + 16 + j) * 8 + f];
    float a_val = a[n * F + ch];
    int rs = row_ptr[n], deg = cnt[n];
    int re = rs + deg;

    float S = 0.f, M = -3.4e38f;
    int i0 = rs + half;
    int s_c = 0, s_n = 0;
    float4 e_c = {0, 0, 0, 0}, e_n = {0, 0, 0, 0};
    unsigned short b_c = 0, b_n = 0;
    if (i0 < re) {
        s_c = src_s[i0];
        e_c = ee_l[i0];
        b_c = b16[s_c * F + ch];
    }
    if (i0 + 2 < re) {
        s_n = src_s[i0 + 2];
        e_n = ee_l[i0 + 2];
        b_n = b16[s_n * F + ch];
    }
    for (int i = i0; i < re; i += 2) {
        int s2 = s_c; float4 e2 = e_c; unsigned short b2 = b_c;
        bool m2 = (i + 4) < re;
        if (m2) { s2 = src_s[i + 4]; e2 = ee_l[i + 4]; }
        // compute current
        union { float4 f4; __half2 h2[4]; } u; u.f4 = e_c;
        float h = __uint_as_float((unsigned)b_c << 16);
#pragma unroll
        for (int q = 0; q < 4; q++) {
            float2 p = __half22float2(u.h2[q]);
            h += p.x * wc8[2 * q] + p.y * wc8[2 * q + 1];
        }
        S += h;
        M = fmaxf(M, h);
        if (m2) b2 = b16[s2 * F + ch];
        s_c = s_n; e_c = e_n; b_c = b_n;
        s_n = s2; e_n = e2; b_n = b2;
    }
    S += __shfl_xor(S, 32, 64);
    M = fmaxf(M, __shfl_xor(M, 32, 64));

    float xv = xin[n * F + ch];
    float sum_h, mean_h, max_h;
    if (deg > 0) {
        sum_h = S + (float)deg * a_val;
        mean_h = sum_h / (float)deg;
        max_h = M + a_val;
    } else {
        sum_h = 0.f; mean_h = 0.f; max_h = 0.f;
    }
    if (half == 0) {
        cat[wv][0 * 32 + ch] = xv;
        cat[wv][1 * 32 + ch] = mean_h;
        cat[wv][2 * 32 + ch] = sum_h;
        cat[wv][3 * 32 + ch] = max_h;
    }
    __syncthreads();
    if (half == 0) {
        float u2 = postb[t * 8 + f];
#pragma unroll
        for (int k = 0; k < 32; k++) {
            int g = k >> 3, kk = k & 7;
            u2 += cat[wv][g * 32 + t * 8 + kk] * postW[(t * 32 + k) * 8 + f];
        }
        um[wv][ch] = u2;
    }
    __syncthreads();
    if (half == 0) {
        float y = linb[ch];
#pragma unroll
        for (int k = 0; k < 32; k++) y += um[wv][k] * linW[k * 32 + ch];
        xout[(size_t)n * F + ch] = fmaxf(y, 0.f);
    }
}

// ---------------- launch ----------------

extern "C" void kernel_launch(void* const* d_in, const int* in_sizes, int n_in,
                              void* d_out, int out_size, void* d_ws, size_t ws_size,
                              hipStream_t stream) {
    const float* x      = (const float*)d_in[0];
    const int*   ei     = (const int*)d_in[1];
    const float* eattr  = (const float*)d_in[2];
    const float* edge_W = (const float*)d_in[3];
    const float* edge_b = (const float*)d_in[4];
    const float* pre_W  = (const float*)d_in[5];
    const float* pre_b  = (const float*)d_in[6];
    const float* post_W = (const float*)d_in[7];
    const float* post_b = (const float*)d_in[8];
    const float* lin_W  = (const float*)d_in[9];
    const float* lin_b  = (const float*)d_in[10];
    float* out = (float*)d_out;

    const size_t NC = (size_t)NN * F;
    char* p = (char*)d_ws;
    float4* ee_pm = (float4*)p;        p += sizeof(float4) * (size_t)NLAYERS * NE; // 128 MB
    float* a      = (float*)p;         p += sizeof(float) * NC;
    float* xb0    = (float*)p;         p += sizeof(float) * NC;
    float* xb1    = (float*)p;         p += sizeof(float) * NC;
    int* cnt      = (int*)p;           p += sizeof(int) * NN;
    int* row_ptr  = (int*)p;           p += sizeof(int) * NN;
    int* cursor   = (int*)p;           p += sizeof(int) * NN;
    int* eid_s    = (int*)p;           p += sizeof(int) * NE;
    int* src_s    = (int*)p;           p += sizeof(int) * NE;
    unsigned short* b16 = (unsigned short*)p;  p += sizeof(unsigned short) * NC;

    dim3 blk(256);
    int gN  = (NN + 255) / 256;
    int gE  = (NE + 255) / 256;
    int gNC = (NN * F + 255) / 256;
    int gG  = NN / 4;

    // CSR build + edge projection (once; reused by all 5 layers)
    hipLaunchKernelGGL(zero_cnt,      dim3(gN), blk, 0, stream, cnt);
    hipLaunchKernelGGL(count_kernel,  dim3(gE), blk, 0, stream, ei, cnt);
    hipLaunchKernelGGL(scan_kernel,   dim3(1), dim3(1024), 0, stream, cnt, row_ptr, cursor);
    hipLaunchKernelGGL(scatter_kernel,dim3(gE), blk, 0, stream, ei, cursor, eid_s, src_s);
    hipLaunchKernelGGL(proj_edges,    dim3(gE), blk, 0, stream, eid_s, eattr,
                       edge_W, edge_b, ee_pm);

    const float* xin = x;
    for (int l = 0; l < NLAYERS; l++) {
        const float* pW  = pre_W  + (size_t)l * T * 24 * FT;
        const float* pb  = pre_b  + (size_t)l * T * FT;
        const float* poW = post_W + (size_t)l * T * 32 * FT;
        const float* pob = post_b + (size_t)l * T * FT;
        const float* lW  = lin_W  + (size_t)l * F * F;
        const float* lb  = lin_b  + (size_t)l * F;
        float* xout = (l == NLAYERS - 1) ? out : ((l & 1) ? xb1 : xb0);

        hipLaunchKernelGGL(node_pre,  dim3(gNC), blk, 0, stream, xin, pW, pb, a, b16);
        hipLaunchKernelGGL(gather_post, dim3(gG), blk, 0, stream,
                           xin, a, b16, ee_pm + (size_t)l * NE,
                           row_ptr, cnt, src_s, pW,
                           poW, pob, lW, lb, xout);
        xin = xout;
    }
}

// Round 5
// 787.543 us; speedup vs baseline: 1.4114x; 1.1691x over previous
//
#include <hip/hip_runtime.h>
#include <hip/hip_fp16.h>

#define NN 50000
#define NE 1600000
#define F 32
#define T 4
#define FT 8
#define ED 16
#define NLAYERS 5

// ---------------- CSR build (once per call; edge_index constant across layers) ----

__global__ void zero_cnt(int* __restrict__ cnt) {
    int i = blockIdx.x * 256 + threadIdx.x;
    if (i < NN) cnt[i] = 0;
}

__global__ void count_kernel(const int* __restrict__ ei, int* __restrict__ cnt) {
    int e = blockIdx.x * 256 + threadIdx.x;
    if (e >= NE) return;
    atomicAdd(&cnt[ei[NE + e]], 1);
}

// one-block exclusive scan over cnt[NN] -> row_ptr, cursor (1024 threads)
__global__ void scan_kernel(const int* __restrict__ cnt, int* __restrict__ row_ptr,
                            int* __restrict__ cursor) {
    __shared__ int wsum[16];
    __shared__ int carry_s;
    int tid = threadIdx.x;
    int lane = tid & 63, wid = tid >> 6;
    if (tid == 0) carry_s = 0;
    __syncthreads();
    for (int base = 0; base < NN; base += 1024) {
        int i = base + tid;
        int v = (i < NN) ? cnt[i] : 0;
        int s = v;
#pragma unroll
        for (int off = 1; off < 64; off <<= 1) {
            int tt = __shfl_up(s, off, 64);
            if (lane >= off) s += tt;
        }
        __syncthreads();
        if (lane == 63) wsum[wid] = s;
        __syncthreads();
        if (wid == 0 && lane < 16) {
            int w = wsum[lane];
            int ws = w;
#pragma unroll
            for (int off = 1; off < 16; off <<= 1) {
                int tt = __shfl_up(ws, off, 16);
                if (lane >= off) ws += tt;
            }
            wsum[lane] = ws - w;
        }
        __syncthreads();
        int excl = carry_s + wsum[wid] + s - v;
        if (i < NN) { row_ptr[i] = excl; cursor[i] = excl; }
        __syncthreads();
        if (tid == 1023) carry_s += wsum[15] + s;
    }
}

// fused scatter + edge projection: read eattr SEQUENTIALLY, compute CSR slot p,
// write src + 5 layers' fp16 ee at p (scattered).
__global__ void build_kernel(const int* __restrict__ ei,
                             const float* __restrict__ eattr,
                             const float* __restrict__ edge_W,  // [L,16,8]
                             const float* __restrict__ edge_b,  // [L,8]
                             int* __restrict__ cursor,
                             int* __restrict__ src_s,
                             float4* __restrict__ ee_pm) {      // [L][NE] float4 (=8 half)
    __shared__ float sW[NLAYERS * ED * FT];   // 640
    __shared__ float sB[NLAYERS * FT];        // 40
    int tid = threadIdx.x;
    for (int k = tid; k < NLAYERS * ED * FT; k += 256) sW[k] = edge_W[k];
    for (int k = tid; k < NLAYERS * FT; k += 256) sB[k] = edge_b[k];
    __syncthreads();
    int e = blockIdx.x * 256 + tid;
    if (e >= NE) return;
    int src = ei[e];
    int dst = ei[NE + e];
    float ea[16];
    const float4* eap = (const float4*)(eattr + (size_t)e * ED);
#pragma unroll
    for (int q = 0; q < 4; q++) {
        float4 v = eap[q];
        ea[q * 4 + 0] = v.x; ea[q * 4 + 1] = v.y;
        ea[q * 4 + 2] = v.z; ea[q * 4 + 3] = v.w;
    }
    int p = atomicAdd(&cursor[dst], 1);
    src_s[p] = src;
#pragma unroll
    for (int l = 0; l < NLAYERS; l++) {
        float v[8];
#pragma unroll
        for (int j = 0; j < 8; j++) v[j] = sB[l * 8 + j];
#pragma unroll
        for (int k = 0; k < 16; k++) {
            float av = ea[k];
#pragma unroll
            for (int j = 0; j < 8; j++) v[j] += av * sW[l * 128 + k * 8 + j];
        }
        union { __half h[8]; float4 f4; } u;
#pragma unroll
        for (int j = 0; j < 8; j++) u.h[j] = __float2half(v[j]);
        ee_pm[(size_t)l * NE + p] = u.f4;
    }
}

// ---------------- per-layer kernels ----------------

__device__ __forceinline__ unsigned short f2bf_rne(float v) {
    unsigned u = __float_as_uint(v);
    return (unsigned short)((u + 0x7FFFu + ((u >> 16) & 1u)) >> 16);
}

// b16[n][ch] = bf16(preW_xj . xt)
__global__ void node_pre(const float* __restrict__ xin,
                         const float* __restrict__ preW,
                         unsigned short* __restrict__ b16) {
    int idx = blockIdx.x * 256 + threadIdx.x;
    if (idx >= NN * F) return;
    int n = idx >> 5, ch = idx & 31;
    int t = ch >> 3, f = ch & 7;
    const float* xrow = xin + n * F + t * FT;
    const float* wB = preW + (t * 24 + 8) * 8 + f;
    float bv = 0.f;
#pragma unroll
    for (int k = 0; k < 8; k++) bv += xrow[k] * wB[k * 8];
    b16[idx] = f2bf_rne(bv);
}

// one wave per dst node; 32 lanes = channels, 2 halves alternate edges.
// 3-deep pipeline (src/ee 3 iters ahead, b16 issued 2 iters after its src).
// Barrier-free: post-MLP entirely via wave shuffles (no LDS).
__global__ __launch_bounds__(256) void gather_post(
        const float* __restrict__ xin,
        const unsigned short* __restrict__ b16,
        const float4* __restrict__ eeL,       // this layer's fp16 ee, CSR order
        const int* __restrict__ row_ptr, const int* __restrict__ cnt,
        const int* __restrict__ src_s,
        const float* __restrict__ preW,       // [T,24,8]
        const float* __restrict__ preb,       // [T,8]
        const float* __restrict__ postW, const float* __restrict__ postb,
        const float* __restrict__ linW, const float* __restrict__ linb,
        float* __restrict__ xout) {
    int tid = threadIdx.x;
    int wv = tid >> 6;
    int lane = tid & 63;
    int ch = lane & 31, half = lane >> 5;
    int n = blockIdx.x * 4 + wv;            // NN divisible by 4
    int t = ch >> 3, f = ch & 7;

    float wc8[8];
#pragma unroll
    for (int j = 0; j < 8; j++) wc8[j] = preW[(t * 24 + 16 + j) * 8 + f];

    int rs = row_ptr[n], deg = cnt[n];
    int re = rs + deg;
    float S = 0.f, M = -3.4e38f;
    int i0 = rs + half;

    int s2 = 0;
    float4 e0 = {0,0,0,0}, e1 = {0,0,0,0}, e2 = {0,0,0,0};
    unsigned short b0 = 0, b1 = 0;
    if (i0 < re)     { int s0 = src_s[i0];     e0 = eeL[i0];     b0 = b16[s0 * F + ch]; }
    if (i0 + 2 < re) { int s1 = src_s[i0 + 2]; e1 = eeL[i0 + 2]; b1 = b16[s1 * F + ch]; }
    if (i0 + 4 < re) { s2 = src_s[i0 + 4];     e2 = eeL[i0 + 4]; }

    for (int i = i0; i < re; i += 2) {
        int s3 = s2; float4 e3 = e2; unsigned short b2 = b1;
        if (i + 6 < re) { s3 = src_s[i + 6]; e3 = eeL[i + 6]; }
        if (i + 4 < re) { b2 = b16[s2 * F + ch]; }
        union { float4 f4; __half2 h2[4]; } u; u.f4 = e0;
        float h = __uint_as_float((unsigned)b0 << 16);
#pragma unroll
        for (int q = 0; q < 4; q++) {
            float2 p2 = __half22float2(u.h2[q]);
            h += p2.x * wc8[2 * q] + p2.y * wc8[2 * q + 1];
        }
        S += h;
        M = fmaxf(M, h);
        e0 = e1; e1 = e2; e2 = e3;
        b0 = b1; b1 = b2;
        s2 = s3;
    }
    S += __shfl_xor(S, 32, 64);
    M = fmaxf(M, __shfl_xor(M, 32, 64));

    float xv = xin[(size_t)n * F + ch];
    // a_val = preb + preW_xi . xt  (own node, via shuffles of xv)
    float a_val = preb[t * 8 + f];
#pragma unroll
    for (int j = 0; j < 8; j++)
        a_val += __shfl(xv, t * 8 + j, 64) * preW[(t * 24 + j) * 8 + f];

    float sum_h, mean_h, max_h;
    if (deg > 0) {
        sum_h = S + (float)deg * a_val;
        mean_h = sum_h / (float)deg;
        max_h = M + a_val;
    } else {
        sum_h = 0.f; mean_h = 0.f; max_h = 0.f;
    }

    // post-MLP per tower: u = postb + [xt|mean|sum|max] @ postW   (via shuffles)
    float u2 = postb[t * 8 + f];
#pragma unroll
    for (int kk = 0; kk < 8; kk++) {
        int sl = t * 8 + kk;
        u2 += __shfl(xv,     sl, 64) * postW[(t * 32 + 0 * 8 + kk) * 8 + f];
        u2 += __shfl(mean_h, sl, 64) * postW[(t * 32 + 1 * 8 + kk) * 8 + f];
        u2 += __shfl(sum_h,  sl, 64) * postW[(t * 32 + 2 * 8 + kk) * 8 + f];
        u2 += __shfl(max_h,  sl, 64) * postW[(t * 32 + 3 * 8 + kk) * 8 + f];
    }
    // final mixing linear + relu
    float y = linb[ch];
#pragma unroll
    for (int k = 0; k < 32; k++)
        y += __shfl(u2, k, 64) * linW[k * 32 + ch];
    if (half == 0)
        xout[(size_t)n * F + ch] = fmaxf(y, 0.f);
}

// ---------------- launch ----------------

extern "C" void kernel_launch(void* const* d_in, const int* in_sizes, int n_in,
                              void* d_out, int out_size, void* d_ws, size_t ws_size,
                              hipStream_t stream) {
    const float* x      = (const float*)d_in[0];
    const int*   ei     = (const int*)d_in[1];
    const float* eattr  = (const float*)d_in[2];
    const float* edge_W = (const float*)d_in[3];
    const float* edge_b = (const float*)d_in[4];
    const float* pre_W  = (const float*)d_in[5];
    const float* pre_b  = (const float*)d_in[6];
    const float* post_W = (const float*)d_in[7];
    const float* post_b = (const float*)d_in[8];
    const float* lin_W  = (const float*)d_in[9];
    const float* lin_b  = (const float*)d_in[10];
    float* out = (float*)d_out;

    const size_t NC = (size_t)NN * F;
    char* p = (char*)d_ws;
    float4* ee_pm = (float4*)p;        p += sizeof(float4) * (size_t)NLAYERS * NE; // 128 MB
    int* src_s    = (int*)p;           p += sizeof(int) * NE;
    int* cnt      = (int*)p;           p += sizeof(int) * NN;
    int* row_ptr  = (int*)p;           p += sizeof(int) * NN;
    int* cursor   = (int*)p;           p += sizeof(int) * NN;
    unsigned short* b16 = (unsigned short*)p;  p += sizeof(unsigned short) * NC;
    float* xb0    = (float*)p;         p += sizeof(float) * NC;
    float* xb1    = (float*)p;         p += sizeof(float) * NC;

    dim3 blk(256);
    int gN  = (NN + 255) / 256;
    int gE  = (NE + 255) / 256;
    int gNC = (NN * F + 255) / 256;
    int gG  = NN / 4;

    // CSR build + fused edge projection (once; reused by all 5 layers)
    hipLaunchKernelGGL(zero_cnt,     dim3(gN), blk, 0, stream, cnt);
    hipLaunchKernelGGL(count_kernel, dim3(gE), blk, 0, stream, ei, cnt);
    hipLaunchKernelGGL(scan_kernel,  dim3(1), dim3(1024), 0, stream, cnt, row_ptr, cursor);
    hipLaunchKernelGGL(build_kernel, dim3(gE), blk, 0, stream, ei, eattr,
                       edge_W, edge_b, cursor, src_s, ee_pm);

    const float* xin = x;
    for (int l = 0; l < NLAYERS; l++) {
        const float* pW  = pre_W  + (size_t)l * T * 24 * FT;
        const float* pb  = pre_b  + (size_t)l * T * FT;
        const float* poW = post_W + (size_t)l * T * 32 * FT;
        const float* pob = post_b + (size_t)l * T * FT;
        const float* lW  = lin_W  + (size_t)l * F * F;
        const float* lb  = lin_b  + (size_t)l * F;
        float* xout = (l == NLAYERS - 1) ? out : ((l & 1) ? xb1 : xb0);

        hipLaunchKernelGGL(node_pre, dim3(gNC), blk, 0, stream, xin, pW, b16);
        hipLaunchKernelGGL(gather_post, dim3(gG), blk, 0, stream,
                           xin, b16, ee_pm + (size_t)l * NE,
                           row_ptr, cnt, src_s, pW, pb,
                           poW, pob, lW, lb, xout);
        xin = xout;
    }
}